// Round 9
// baseline (630.386 us; speedup 1.0000x reference)
//
#include <hip/hip_runtime.h>
#include <hip/hip_cooperative_groups.h>

namespace cg = cooperative_groups;

// SELayer3D: out = x * sigmoid(relu(segment_mean(x, bidx) @ W1) @ W2)[bidx]
// N=1e6, C=128, CR=8, B=8. Memory-bound; minimal traffic = 1.0-1.5GB.
//
// Single cooperative kernel (1024 blocks x 256 thr, 4 blocks/CU co-resident):
//   init (block 0 zeroes sums/bnd) -> grid.sync
//   phase A: each block sums its contiguous chunk (inline boundary detect)
//   -> threadfence + grid.sync
//   phase B: each block computes all 8 gates from sums (redundant, ~16K MACs)
//            then scales its OWN chunk BACKWARD (youngest-in-L3 lines first),
//            NT stores for out (no L3 pollution).
// This removes 3 launch boundaries vs the 4-kernel version and makes the
// whole op one ~260us dispatch (visible in rocprof top-5).

constexpr int C    = 128;
constexpr int CR   = 8;
constexpr int B    = 8;
constexpr int GRID = 1024;

typedef float f32x4 __attribute__((ext_vector_type(4)));

__global__ __launch_bounds__(256, 4) void k_fused(
    const float* __restrict__ x, const float* __restrict__ W1,
    const float* __restrict__ W2, const int* __restrict__ coors,
    float* __restrict__ sums, int* __restrict__ bnd,
    float* __restrict__ out, int N)
{
    cg::grid_group grid = cg::this_grid();

    const int tid     = threadIdx.x;
    const int col4    = tid & 31;
    const int rowlane = tid >> 5;
    const f32x4* __restrict__ x4 = (const f32x4*)x;

    const int rpb = (N + GRID - 1) / GRID;
    const int r0  = min((int)blockIdx.x * rpb, N);
    const int r1  = min(r0 + rpb, N);

    // ---- init: block 0 zeroes sums, inits bnd ----
    if (blockIdx.x == 0) {
        for (int i = tid; i < B * C; i += 256) sums[i] = 0.f;
        if (tid <= B) bnd[tid] = (tid == 0) ? 0 : N;
    }
    grid.sync();

    // ---- phase A: column sums of own chunk + boundary detection ----
    __shared__ f32x4 lds4[8][32];
    if (r0 < r1) {
        const int b_first = coors[r0 * 4];
        const int b_last  = coors[(r1 - 1) * 4];

        // boundary at chunk start
        if (tid == 0) {
            int bp = (r0 == 0) ? -1 : coors[(r0 - 1) * 4];
            if (bp != b_first) {
                int lo = max(bp + 1, 1), hi = min(b_first, B - 1);
                for (int b = lo; b <= hi; ++b) bnd[b] = r0;
            }
        }

        if (b_first == b_last) {
            // fast path: single batch
            if ((unsigned)b_first < (unsigned)B) {
                f32x4 acc = {0.f, 0.f, 0.f, 0.f};
                #pragma unroll 4
                for (int r = r0 + rowlane; r < r1; r += 8)
                    acc += x4[r * 32 + col4];
                lds4[rowlane][col4] = acc;
                __syncthreads();
                if (tid < C) {
                    const float* lf = (const float*)lds4;
                    float s = 0.f;
                    #pragma unroll
                    for (int rl = 0; rl < 8; ++rl) s += lf[rl * C + tid];
                    atomicAdd(&sums[b_first * C + tid], s);
                }
            }
        } else {
            // slow path: straddles boundaries (<=7 blocks)
            f32x4 acc = {0.f, 0.f, 0.f, 0.f};
            int cur_b = -1;
            for (int r = r0 + rowlane; r < r1; r += 8) {
                int b = coors[r * 4];
                if (col4 == 0 && r > r0) {      // in-chunk boundary detect
                    int bp = coors[(r - 1) * 4];
                    if (bp != b) {
                        int lo = max(bp + 1, 1), hi = min(b, B - 1);
                        for (int bb = lo; bb <= hi; ++bb) bnd[bb] = r;
                    }
                }
                if (b != cur_b) {
                    if ((unsigned)cur_b < (unsigned)B) {
                        float* s = &sums[cur_b * C + col4 * 4];
                        atomicAdd(s + 0, acc.x); atomicAdd(s + 1, acc.y);
                        atomicAdd(s + 2, acc.z); atomicAdd(s + 3, acc.w);
                    }
                    cur_b = b;
                    acc = (f32x4){0.f, 0.f, 0.f, 0.f};
                }
                acc += x4[r * 32 + col4];
            }
            if ((unsigned)cur_b < (unsigned)B) {
                float* s = &sums[cur_b * C + col4 * 4];
                atomicAdd(s + 0, acc.x); atomicAdd(s + 1, acc.y);
                atomicAdd(s + 2, acc.z); atomicAdd(s + 3, acc.w);
            }
        }
    }
    __threadfence();
    grid.sync();

    // ---- phase B: gates (all 8, redundant per block) + scale own chunk ----
    __shared__ float gate_s[B][C];
    __shared__ float hbuf[B][CR];
    __shared__ int   bnd_s[B + 1];

    if (tid <= B) bnd_s[tid] = bnd[tid];
    __syncthreads();

    {
        const int j = tid >> 5, l = tid & 31;   // 8 groups x 32 lanes
        for (int b = 0; b < B; ++b) {
            float p = 0.f;
            #pragma unroll
            for (int k = 0; k < 4; ++k) {
                int c = l + 32 * k;
                p += sums[b * C + c] * W1[c * CR + j];
            }
            #pragma unroll
            for (int off = 16; off; off >>= 1) p += __shfl_xor(p, off);
            if (l == 0) {
                float rcnt = 1.0f / fmaxf((float)(bnd_s[b + 1] - bnd_s[b]), 1.0f);
                hbuf[b][j] = fmaxf(p * rcnt, 0.f);
            }
        }
    }
    __syncthreads();
    for (int i = tid; i < B * C; i += 256) {
        int b = i >> 7, c = i & (C - 1);
        float s = 0.f;
        #pragma unroll
        for (int j = 0; j < CR; ++j) s += hbuf[b][j] * W2[j * C + c];
        gate_s[b][c] = 1.f / (1.f + expf(-s));
    }
    __syncthreads();

    if (r0 < r1) {
        f32x4* __restrict__ o4 = (f32x4*)out;
        const f32x4* __restrict__ g4 = (const f32x4*)&gate_s[0][0];

        int b0 = 0, b1 = 0;
        #pragma unroll
        for (int i = 1; i < B; ++i) {
            b0 += (r0 >= bnd_s[i]);
            b1 += (r1 - 1 >= bnd_s[i]);
        }

        const int nsteps = (r1 - r0 + 7) >> 3;
        if (b0 == b1) {
            // fast path: uniform gate, backward walk (harvest L3-young lines)
            const f32x4 g = g4[b0 * 32 + col4];
            for (int rb = nsteps - 1; rb >= 0; --rb) {
                int r = r0 + rb * 8 + rowlane;
                if (r < r1) {
                    f32x4 v = x4[r * 32 + col4];
                    __builtin_nontemporal_store(v * g, &o4[r * 32 + col4]);
                }
            }
        } else {
            // boundary block: per-row batch via register compares
            for (int rb = nsteps - 1; rb >= 0; --rb) {
                int r = r0 + rb * 8 + rowlane;
                if (r < r1) {
                    int b = 0;
                    #pragma unroll
                    for (int i = 1; i < B; ++i) b += (r >= bnd_s[i]);
                    f32x4 g = g4[b * 32 + col4];
                    f32x4 v = x4[r * 32 + col4];
                    __builtin_nontemporal_store(v * g, &o4[r * 32 + col4]);
                }
            }
        }
    }
}

extern "C" void kernel_launch(void* const* d_in, const int* in_sizes, int n_in,
                              void* d_out, int out_size, void* d_ws, size_t ws_size,
                              hipStream_t stream)
{
    const float* x     = (const float*)d_in[0];
    const float* W1    = (const float*)d_in[1];
    const float* W2    = (const float*)d_in[2];
    const int*   coors = (const int*)d_in[3];
    // d_in[4] = batch_size scalar (B=8 fixed by problem spec)

    int N = in_sizes[0] / C;

    float* sums = (float*)d_ws;          // B*C floats
    int*   bnd  = (int*)(sums + B * C);  // B+1 ints
    float* out  = (float*)d_out;

    void* args[] = { (void*)&x, (void*)&W1, (void*)&W2, (void*)&coors,
                     (void*)&sums, (void*)&bnd, (void*)&out, (void*)&N };
    hipLaunchCooperativeKernel((const void*)k_fused, dim3(GRID), dim3(256),
                               args, 0, stream);
}